// Round 5
// baseline (484.794 us; speedup 1.0000x reference)
//
#include <hip/hip_runtime.h>
#include <cmath>

#define NUM_S   64
#define IMG_H   256
#define IMG_W   256
#define HWSZ    (IMG_H*IMG_W)          // 65536
#define HW4     (HWSZ/4)               // 16384 float4s per slice
#define BATCH   2
#define NPIX    (BATCH*HWSZ)           // 131072
#define NEL     (BATCH*NUM_S*HWSZ)     // 8388608
#define NSLICE  (BATCH*NUM_S)          // 128
#define VALID   246
#define INV_T   2.0f                   // 1/TEMP, TEMP=0.5
#define EPS_F   1e-20f
#define C1_F    1e-4f
#define C2_F    9e-4f

struct GK { float g[11]; };

// block-wide sum of a float, one double atomicAdd per block
__device__ inline void block_atomic_add(float v, double* dst) {
    __shared__ float sm[8];
    __syncthreads();                       // protect sm across repeated calls
    #pragma unroll
    for (int off = 32; off; off >>= 1) v += __shfl_down(v, off, 64);
    int lane = threadIdx.x & 63, w = threadIdx.x >> 6;
    if (lane == 0) sm[w] = v;
    __syncthreads();
    if (threadIdx.x == 0) {
        double s = 0.0;
        int nw = blockDim.x >> 6;
        for (int i = 0; i < nw; ++i) s += (double)sm[i];
        atomicAdd(dst, s);
    }
}

// Kernel 1: per-pixel online-softmax scan, float4-vectorized (4 pixels per
// thread, 16B/lane loads + next-slice prefetch). Stores {p,cummax} pairs.
__global__ __launch_bounds__(256) void scan_kernel(
    const float* __restrict__ img, const float* __restrict__ tgt,
    const float* __restrict__ un,
    float2* __restrict__ pt1, float2* __restrict__ pt2,
    double* __restrict__ acc)
{
    int tid = blockIdx.x * 256 + threadIdx.x;
    bool bwd = tid >= (NPIX / 4);           // uniform per block
    int p4 = bwd ? tid - NPIX / 4 : tid;
    int b   = p4 >> 14;                     // p4 / HW4
    int hw4 = p4 & (HW4 - 1);
    int base4 = b * (NUM_S * HW4) + hw4;
    int idx  = base4 + (bwd ? (NUM_S - 1) * HW4 : 0);
    int step = bwd ? -HW4 : HW4;
    const float4* __restrict__ img4 = (const float4*)img;
    const float4* __restrict__ tgt4 = (const float4*)tgt;
    const float4* __restrict__ un4  = (const float4*)un;
    float4* __restrict__ out4 = (float4*)(bwd ? pt2 : pt1);

    float m[4], num[4], den[4], tm[4];
    #pragma unroll
    for (int c = 0; c < 4; ++c) { m[c] = -INFINITY; num[c] = 0.f; den[c] = 0.f; tm[c] = -INFINITY; }
    float l1x = 0.f, l1p = 0.f;

    float4 x = img4[idx], u = un4[idx], t = tgt4[idx];
    for (int i = 0; i < NUM_S; ++i) {
        int nidx = idx + step;
        float4 xn = make_float4(0.f, 0.f, 0.f, 0.f);
        float4 unn = xn, tn = xn;
        if (i < NUM_S - 1) { xn = img4[nidx]; unn = un4[nidx]; tn = tgt4[nidx]; }
        float xc[4] = {x.x, x.y, x.z, x.w};
        float uc[4] = {u.x, u.y, u.z, u.w};
        float tc[4] = {t.x, t.y, t.z, t.w};
        float p[4];
        #pragma unroll
        for (int c = 0; c < 4; ++c) {
            float gmb = -__logf(-__logf(uc[c] + EPS_F) + EPS_F);
            float yv = xc[c] + gmb;
            float mn = fmaxf(m[c], yv);              // online softmax
            float sc = __expf((m[c] - mn) * INV_T);  // m=-inf first iter -> 0
            float e  = __expf((yv - mn) * INV_T);
            num[c] = num[c] * sc + e * xc[c];
            den[c] = den[c] * sc + e;
            m[c] = mn;
            p[c] = num[c] / den[c];
            tm[c] = fmaxf(tm[c], tc[c]);
            if (!bwd) l1x += fabsf(xc[c] - tc[c]);
            l1p += fabsf(p[c] - tm[c]);
        }
        out4[2 * idx]     = make_float4(p[0], tm[0], p[1], tm[1]);
        out4[2 * idx + 1] = make_float4(p[2], tm[2], p[3], tm[3]);
        idx = nidx; x = xn; u = unn; t = tn;
    }
    block_atomic_add(l1x, &acc[0]);
    block_atomic_add(l1p, bwd ? &acc[2] : &acc[1]);
}

// Kernel 2: fused separable-Gaussian SSIM for one pair (blockIdx.z).
// 32x32 output tile, 256 threads, LDS 5*32*44*4 = 27.5 KB.
// Overhead-minimized: interior blocks (ty<7) take a clamp-free base-pointer
// load path; squares computed once via k-outer sliding FIR; %11 replaced by
// incremental conditional subtract. Swizzle (g+3r)%11 on float4 groups.
__global__ __launch_bounds__(256) void ssim_kernel(
    const float* __restrict__ img, const float* __restrict__ tgt,
    const float2* __restrict__ pt1, const float2* __restrict__ pt2,
    GK gk, double* __restrict__ acc)
{
    __shared__ float v[5][32 * 44];
    int pair = blockIdx.z;
    int base = blockIdx.y * HWSZ;         // slice base
    int ty = blockIdx.x >> 3, tx = blockIdx.x & 7;
    int r0 = ty * 32, c0 = tx * 32;       // output-tile origin
    int rmax = min(32, VALID - r0);
    int cmax = min(32, VALID - c0);

    // ---- vertical blur: 42 cols x 4 row-groups(8 rows) = 168 tasks ----
    int task = threadIdx.x;
    if (task < 168) {
        int c  = task % 42;
        int rb = (task / 42) * 8;
        int gc = min(c0 + c, IMG_W - 1);   // one min per thread
        int rowoff = r0 + rb;
        float ax[18], ay[18];
        if (ty < 7) {                      // interior: clamp-free loads
            if (pair == 0) {
                const float* __restrict__ px = img + base + rowoff * IMG_W + gc;
                const float* __restrict__ py = tgt + base + rowoff * IMG_W + gc;
                #pragma unroll
                for (int k = 0; k < 18; ++k) { ax[k] = px[k * IMG_W]; ay[k] = py[k * IMG_W]; }
            } else {
                const float2* __restrict__ pp =
                    (pair == 1 ? pt1 : pt2) + base + rowoff * IMG_W + gc;
                #pragma unroll
                for (int k = 0; k < 18; ++k) { float2 w = pp[k * IMG_W]; ax[k] = w.x; ay[k] = w.y; }
            }
        } else {                           // edge rows: clamp address only
            if (pair == 0) {
                #pragma unroll
                for (int k = 0; k < 18; ++k) {
                    int gr = min(rowoff + k, IMG_H - 1);
                    int id = base + gr * IMG_W + gc;
                    ax[k] = img[id]; ay[k] = tgt[id];
                }
            } else {
                const float2* __restrict__ pp = (pair == 1 ? pt1 : pt2);
                #pragma unroll
                for (int k = 0; k < 18; ++k) {
                    int gr = min(rowoff + k, IMG_H - 1);
                    float2 w = pp[base + gr * IMG_W + gc];
                    ax[k] = w.x; ay[k] = w.y;
                }
            }
        }
        // k-outer sliding FIR: each square computed exactly once
        float sx[8], sy[8], sxx[8], syy[8], sxy[8];
        #pragma unroll
        for (int j = 0; j < 8; ++j) { sx[j] = sy[j] = sxx[j] = syy[j] = sxy[j] = 0.f; }
        #pragma unroll
        for (int k = 0; k < 18; ++k) {
            float xv = ax[k], yv = ay[k];
            float xx = xv * xv, yy = yv * yv, xy = xv * yv;
            #pragma unroll
            for (int j = 0; j < 8; ++j) {
                if (k - j >= 0 && k - j < 11) {      // folds at compile time
                    float w = gk.g[k - j];
                    sx[j]  += w * xv; sy[j]  += w * yv;
                    sxx[j] += w * xx; syy[j] += w * yy; sxy[j] += w * xy;
                }
            }
        }
        int cg = c >> 2, cm = c & 3;
        int pg = (cg + 3 * rb) % 11;                 // one mod per thread
        #pragma unroll
        for (int j = 0; j < 8; ++j) {
            int row = rb + j;
            int ad  = row * 44 + pg * 4 + cm;
            v[0][ad] = sx[j];  v[1][ad] = sy[j];
            v[2][ad] = sxx[j]; v[3][ad] = syy[j]; v[4][ad] = sxy[j];
            pg += 3; if (pg >= 11) pg -= 11;         // incremental swizzle
        }
    }
    __syncthreads();

    // ---- horizontal blur + SSIM: 32 rows x 8 col-groups(4 cols) = 256 ----
    float lsum = 0.f;
    {
        int r   = threadIdx.x >> 3;        // 0..31
        int cbg = threadIdx.x & 7;         // 0..7
        int cb  = cbg * 4;
        if (r < rmax) {
            int pg0 = (cbg + 3 * r) % 11;  // one mod per thread
            float o[5][4];
            #pragma unroll
            for (int f = 0; f < 5; ++f) {   // per-field: only t[16] live
                float t[16];
                int pg = pg0;
                #pragma unroll
                for (int g4 = 0; g4 < 4; ++g4) {
                    float4 q = *(const float4*)&v[f][r * 44 + pg * 4];
                    t[g4*4+0] = q.x; t[g4*4+1] = q.y;
                    t[g4*4+2] = q.z; t[g4*4+3] = q.w;
                    pg += 1; if (pg >= 11) pg -= 11;
                }
                // tap windows: o[j] = sum_{k=j..j+10} g[k-j]*t[k]
                // (upper bounds matter: t[14],t[15] must only meet g[<11];
                //  R4's missing bound read gk.g[11..12] OOB -> NaN)
                float s0 = 0.f, s1 = 0.f, s2 = 0.f, s3 = 0.f;
                #pragma unroll
                for (int k = 0; k < 16; ++k) {
                    float tv = t[k];
                    if (k < 11)           s0 += gk.g[k]     * tv;
                    if (k >= 1 && k < 12) s1 += gk.g[k - 1] * tv;
                    if (k >= 2 && k < 13) s2 += gk.g[k - 2] * tv;
                    if (k >= 3 && k < 14) s3 += gk.g[k - 3] * tv;
                }
                o[f][0] = s0; o[f][1] = s1; o[f][2] = s2; o[f][3] = s3;
            }
            #pragma unroll
            for (int j = 0; j < 4; ++j) {
                if (cb + j < cmax) {
                    float m1 = o[0][j], m2 = o[1][j];
                    float s11 = o[2][j] - m1 * m1;
                    float s22 = o[3][j] - m2 * m2;
                    float s12 = o[4][j] - m1 * m2;
                    float nv = (2.f * m1 * m2 + C1_F) * (2.f * s12 + C2_F);
                    float dv = (m1 * m1 + m2 * m2 + C1_F) * (s11 + s22 + C2_F);
                    lsum += nv / dv;
                }
            }
        }
    }
    block_atomic_add(lsum, &acc[3 + pair]);
}

__global__ void finalize_kernel(const double* __restrict__ acc,
                                float* __restrict__ out) {
    double l1 = (acc[0] + acc[1] + acc[2]) / (double)NEL;
    double ss = (acc[3] + acc[4] + acc[5]) /
                ((double)NSLICE * (double)VALID * (double)VALID);
    out[0] = (float)(3.0 + l1 - ss);
}

extern "C" void kernel_launch(void* const* d_in, const int* in_sizes, int n_in,
                              void* d_out, int out_size, void* d_ws, size_t ws_size,
                              hipStream_t stream) {
    const float* img = (const float*)d_in[0];
    const float* tgt = (const float*)d_in[1];
    const float* un  = (const float*)d_in[2];
    float* out = (float*)d_out;

    // workspace: pt1, pt2 (float2[NEL] each, 64MB each) + 6 double accums
    float2* pt1 = (float2*)d_ws;
    float2* pt2 = pt1 + NEL;
    double* acc = (double*)(pt2 + NEL);

    hipMemsetAsync(acc, 0, 6 * sizeof(double), stream);

    GK gk;  // gaussian(11, sigma=1.5) computed in double, matches reference
    {
        double c[11], s = 0.0;
        for (int i = 0; i < 11; ++i) { double d = i - 5; c[i] = exp(-d * d / 4.5); s += c[i]; }
        for (int i = 0; i < 11; ++i) gk.g[i] = (float)(c[i] / s);
    }

    scan_kernel<<<(2 * (NPIX / 4)) / 256, 256, 0, stream>>>(img, tgt, un, pt1, pt2, acc);
    ssim_kernel<<<dim3(64, NSLICE, 3), 256, 0, stream>>>(img, tgt, pt1, pt2, gk, acc);
    finalize_kernel<<<1, 1, 0, stream>>>(acc, out);
}

// Round 6
// 276.006 us; speedup vs baseline: 1.7565x; 1.7565x over previous
//
#include <hip/hip_runtime.h>
#include <cmath>
#include <cstring>

#define NUM_S   64
#define IMG_H   256
#define IMG_W   256
#define HWSZ    (IMG_H*IMG_W)          // 65536
#define BATCH   2
#define NPIX    (BATCH*HWSZ)           // 131072
#define NEL     (BATCH*NUM_S*HWSZ)     // 8388608
#define NSLICE  (BATCH*NUM_S)          // 128
#define VALID   246
#define INV_T   2.0f                   // 1/TEMP
#define EPS_F   1e-20f
#define C1_F    1e-4f
#define C2_F    9e-4f
#define RS      280                    // V_lds row stride in bf16 (560 B, 16B-aligned)

using fragB = __attribute__((ext_vector_type(8))) short;  // 8 bf16
using fragC = __attribute__((ext_vector_type(4))) float;  // 4 fp32

struct GB { short h[11]; };            // bf16 bits of gaussian taps (sum ~= 1)

__device__ inline short f2bf(float v) {          // RNE float->bf16 (finite inputs)
    unsigned u = __float_as_uint(v);
    return (short)((u + 0x7fffu + ((u >> 16) & 1u)) >> 16);
}

__device__ inline void block_atomic_add(float v, double* dst) {
    __shared__ float sm[8];
    __syncthreads();
    #pragma unroll
    for (int off = 32; off; off >>= 1) v += __shfl_down(v, off, 64);
    int lane = threadIdx.x & 63, w = threadIdx.x >> 6;
    if (lane == 0) sm[w] = v;
    __syncthreads();
    if (threadIdx.x == 0) {
        double s = 0.0;
        int nw = blockDim.x >> 6;
        for (int i = 0; i < nw; ++i) s += (double)sm[i];
        atomicAdd(dst, s);
    }
}

// Kernel 1: per-pixel online-softmax scan over slices. float2 = 2 pixels per
// thread (grid 512 blocks = 2/CU; R5's float4 gave only 1 block/CU), prefetch
// depth 2. Stores {p,cummax} float2 pairs as one float4.
__global__ __launch_bounds__(256) void scan_kernel(
    const float* __restrict__ img, const float* __restrict__ tgt,
    const float* __restrict__ un,
    float2* __restrict__ pt1, float2* __restrict__ pt2,
    double* __restrict__ acc)
{
    const int HW2 = HWSZ / 2;
    int tid = blockIdx.x * 256 + threadIdx.x;
    bool bwd = tid >= (NPIX / 2);
    int p2 = bwd ? tid - NPIX / 2 : tid;
    int b   = p2 >> 15;                     // p2 / HW2
    int hw2 = p2 & (HW2 - 1);
    int idx  = b * (NUM_S * HW2) + hw2 + (bwd ? (NUM_S - 1) * HW2 : 0);
    int step = bwd ? -HW2 : HW2;
    const float2* __restrict__ img2 = (const float2*)img;
    const float2* __restrict__ tgt2 = (const float2*)tgt;
    const float2* __restrict__ un2  = (const float2*)un;
    float4* __restrict__ out4 = (float4*)(bwd ? pt2 : pt1);

    float m[2], num[2], den[2], tm[2];
    #pragma unroll
    for (int c = 0; c < 2; ++c) { m[c] = -INFINITY; num[c] = 0.f; den[c] = 0.f; tm[c] = -INFINITY; }
    float l1x = 0.f, l1p = 0.f;

    float2 xb[2], ub[2], tb[2];
    xb[0] = img2[idx];        ub[0] = un2[idx];        tb[0] = tgt2[idx];
    xb[1] = img2[idx + step]; ub[1] = un2[idx + step]; tb[1] = tgt2[idx + step];

    for (int i = 0; i < NUM_S; ++i) {
        int buf = i & 1;
        float2 x = xb[buf], u = ub[buf], t = tb[buf];
        if (i + 2 < NUM_S) {                 // refill this slot 2 slices ahead
            int id2 = idx + 2 * step;
            xb[buf] = img2[id2]; ub[buf] = un2[id2]; tb[buf] = tgt2[id2];
        }
        float xc[2] = {x.x, x.y}, uc[2] = {u.x, u.y}, tc[2] = {t.x, t.y};
        float p[2];
        #pragma unroll
        for (int c = 0; c < 2; ++c) {
            float gmb = -__logf(-__logf(uc[c] + EPS_F) + EPS_F);
            float yv = xc[c] + gmb;
            float mn = fmaxf(m[c], yv);              // online softmax
            float sc = __expf((m[c] - mn) * INV_T);  // m=-inf first iter -> 0
            float e  = __expf((yv - mn) * INV_T);
            num[c] = num[c] * sc + e * xc[c];
            den[c] = den[c] * sc + e;
            m[c] = mn;
            p[c] = num[c] / den[c];
            tm[c] = fmaxf(tm[c], tc[c]);
            if (!bwd) l1x += fabsf(xc[c] - tc[c]);
            l1p += fabsf(p[c] - tm[c]);
        }
        out4[idx] = make_float4(p[0], tm[0], p[1], tm[1]);
        idx += step;
    }
    block_atomic_add(l1x, &acc[0]);
    block_atomic_add(l1p, bwd ? &acc[2] : &acc[1]);
}

// Kernel 2: MFMA-based separable-Gaussian SSIM.
// Block = 16 output rows (stripe) x 256 cols of one (slice,pair); 256 thr.
// Stage 1 (vertical): D16x16 = A(16x32 const band) . B(32 rows x 16 cols of
// field data, built in-reg from global) -- ONE mfma per tile per field.
// V -> LDS as bf16 (row-major, RS=280, pad cols zeroed: MFMA 0*NaN poisons!).
// Stage 2 (horizontal): D = A(V rows via ds_read_b128) . B(const band).
// Epilogue: pointwise SSIM on C-layout regs, mask r,c >= 246, block-reduce.
__global__ __launch_bounds__(256) void ssim_kernel(
    const float* __restrict__ img, const float* __restrict__ tgt,
    const float2* __restrict__ pt1, const float2* __restrict__ pt2,
    GB gb, double* __restrict__ acc)
{
    __shared__ short Vl[5][16 * RS];       // 44800 B
    int pair  = blockIdx.z;
    int base  = blockIdx.y * HWSZ;
    int r0    = blockIdx.x * 16;
    int lane  = threadIdx.x & 63;
    int wid   = threadIdx.x >> 6;          // 0..3
    int q     = lane >> 4;                 // 0..3
    int n     = lane & 15;

    // constant band fragment: value = g[(q*8+j) - n], zero outside band.
    // Serves as A in stage 1 (A[m=lane&15][k=q*8+j] = g[k-m]) and as B in
    // stage 2 (B[k=q*8+j][n=lane&15] = g[k-n]).
    fragB band;
    #pragma unroll
    for (int j = 0; j < 8; ++j) {
        int kk = q * 8 + j - n;
        short hv = 0;
        #pragma unroll
        for (int w = 0; w < 11; ++w) hv = (kk == w) ? gb.h[w] : hv;
        band[j] = hv;
    }

    // zero the pad cols [256, RS) of all 5 fields (960 dwords)
    for (int d = threadIdx.x; d < 960; d += 256) {
        int f = d / 192, rm = d % 192, r = rm / 12, cc = rm % 12;
        ((int*)Vl)[f * 2240 + r * 140 + 128 + cc] = 0;
    }

    bool clampR = (r0 == 240);             // last stripe needs row clamping
    const fragC zero = {0.f, 0.f, 0.f, 0.f};

    // ---- stage 1: 4 c-tiles per wave ----
    for (int it = 0; it < 4; ++it) {
        int ct = wid * 4 + it;
        int c0 = ct * 16;
        int col = c0 + n;
        float xr[8], yr[8];
        if (pair == 0) {
            if (!clampR) {
                const float* px = img + base + (r0 + q * 8) * IMG_W + col;
                const float* py = tgt + base + (r0 + q * 8) * IMG_W + col;
                #pragma unroll
                for (int j = 0; j < 8; ++j) { xr[j] = px[j * IMG_W]; yr[j] = py[j * IMG_W]; }
            } else {
                #pragma unroll
                for (int j = 0; j < 8; ++j) {
                    int rr = min(r0 + q * 8 + j, IMG_H - 1);   // finite garbage only
                    xr[j] = img[base + rr * IMG_W + col];
                    yr[j] = tgt[base + rr * IMG_W + col];
                }
            }
        } else {
            const float2* __restrict__ pp = (pair == 1 ? pt1 : pt2) + base;
            if (!clampR) {
                const float2* p0 = pp + (r0 + q * 8) * IMG_W + col;
                #pragma unroll
                for (int j = 0; j < 8; ++j) { float2 w = p0[j * IMG_W]; xr[j] = w.x; yr[j] = w.y; }
            } else {
                #pragma unroll
                for (int j = 0; j < 8; ++j) {
                    int rr = min(r0 + q * 8 + j, IMG_H - 1);
                    float2 w = pp[rr * IMG_W + col];
                    xr[j] = w.x; yr[j] = w.y;
                }
            }
        }
        fragB fX, fY, fXX, fYY, fXY;
        #pragma unroll
        for (int j = 0; j < 8; ++j) {
            float xv = xr[j], yv = yr[j];
            fX[j]  = f2bf(xv);      fY[j]  = f2bf(yv);
            fXX[j] = f2bf(xv * xv); fYY[j] = f2bf(yv * yv);
            fXY[j] = f2bf(xv * yv);
        }
        fragC v0 = __builtin_amdgcn_mfma_f32_16x16x32_bf16(band, fX,  zero, 0, 0, 0);
        fragC v1 = __builtin_amdgcn_mfma_f32_16x16x32_bf16(band, fY,  zero, 0, 0, 0);
        fragC v2 = __builtin_amdgcn_mfma_f32_16x16x32_bf16(band, fXX, zero, 0, 0, 0);
        fragC v3 = __builtin_amdgcn_mfma_f32_16x16x32_bf16(band, fYY, zero, 0, 0, 0);
        fragC v4 = __builtin_amdgcn_mfma_f32_16x16x32_bf16(band, fXY, zero, 0, 0, 0);
        // C-layout: row = q*4+reg, col = n  -> V_lds[f][row*RS + col]
        #pragma unroll
        for (int reg = 0; reg < 4; ++reg) {
            int ro = (q * 4 + reg) * RS + col;
            Vl[0][ro] = f2bf(v0[reg]); Vl[1][ro] = f2bf(v1[reg]);
            Vl[2][ro] = f2bf(v2[reg]); Vl[3][ro] = f2bf(v3[reg]);
            Vl[4][ro] = f2bf(v4[reg]);
        }
    }
    __syncthreads();

    // ---- stage 2 + epilogue: 4 c-tiles per wave ----
    float lsum = 0.f;
    for (int it = 0; it < 4; ++it) {
        int ct = wid * 4 + it;
        int c0 = ct * 16;
        int ao = n * RS + c0 + q * 8;      // A[m=lane&15][k=q*8+j], 16B aligned
        fragB a0 = *(const fragB*)&Vl[0][ao];
        fragB a1 = *(const fragB*)&Vl[1][ao];
        fragB a2 = *(const fragB*)&Vl[2][ao];
        fragB a3 = *(const fragB*)&Vl[3][ao];
        fragB a4 = *(const fragB*)&Vl[4][ao];
        fragC o0 = __builtin_amdgcn_mfma_f32_16x16x32_bf16(a0, band, zero, 0, 0, 0);
        fragC o1 = __builtin_amdgcn_mfma_f32_16x16x32_bf16(a1, band, zero, 0, 0, 0);
        fragC o2 = __builtin_amdgcn_mfma_f32_16x16x32_bf16(a2, band, zero, 0, 0, 0);
        fragC o3 = __builtin_amdgcn_mfma_f32_16x16x32_bf16(a3, band, zero, 0, 0, 0);
        fragC o4 = __builtin_amdgcn_mfma_f32_16x16x32_bf16(a4, band, zero, 0, 0, 0);
        #pragma unroll
        for (int reg = 0; reg < 4; ++reg) {
            int r = r0 + q * 4 + reg;      // C-layout row
            int c = c0 + n;                // C-layout col
            if (r < VALID && c < VALID) {
                float m1 = o0[reg], m2 = o1[reg];
                float s11 = o2[reg] - m1 * m1;
                float s22 = o3[reg] - m2 * m2;
                float s12 = o4[reg] - m1 * m2;
                float nv = (2.f * m1 * m2 + C1_F) * (2.f * s12 + C2_F);
                float dv = (m1 * m1 + m2 * m2 + C1_F) * (s11 + s22 + C2_F);
                lsum += nv / dv;
            }
        }
    }
    block_atomic_add(lsum, &acc[3 + pair]);
}

__global__ void finalize_kernel(const double* __restrict__ acc,
                                float* __restrict__ out) {
    double l1 = (acc[0] + acc[1] + acc[2]) / (double)NEL;
    double ss = (acc[3] + acc[4] + acc[5]) /
                ((double)NSLICE * (double)VALID * (double)VALID);
    out[0] = (float)(3.0 + l1 - ss);
}

extern "C" void kernel_launch(void* const* d_in, const int* in_sizes, int n_in,
                              void* d_out, int out_size, void* d_ws, size_t ws_size,
                              hipStream_t stream) {
    const float* img = (const float*)d_in[0];
    const float* tgt = (const float*)d_in[1];
    const float* un  = (const float*)d_in[2];
    float* out = (float*)d_out;

    float2* pt1 = (float2*)d_ws;           // 64 MB
    float2* pt2 = pt1 + NEL;               // 64 MB
    double* acc = (double*)(pt2 + NEL);

    hipMemsetAsync(acc, 0, 6 * sizeof(double), stream);

    // gaussian(11, 1.5) in double; bf16-renormalize so the bf16 taps sum to ~1
    // (uncorrected bf16 weight-sum error would bias sigma12 vs C2=9e-4).
    GB gb;
    {
        double g[11], s = 0.0;
        for (int i = 0; i < 11; ++i) { double d = i - 5; g[i] = exp(-d * d / 4.5); s += g[i]; }
        for (int i = 0; i < 11; ++i) g[i] /= s;
        for (int iter = 0; iter < 3; ++iter) {
            double sb = 0.0;
            short h[11];
            for (int i = 0; i < 11; ++i) {
                float f = (float)g[i];
                unsigned u; memcpy(&u, &f, 4);
                h[i] = (short)((u + 0x7fffu + ((u >> 16) & 1u)) >> 16);
                unsigned ub = ((unsigned)(unsigned short)h[i]) << 16;
                float fb; memcpy(&fb, &ub, 4);
                sb += fb;
            }
            for (int i = 0; i < 11; ++i) { g[i] /= sb; gb.h[i] = h[i]; }
        }
    }

    scan_kernel<<<NPIX / 256, 256, 0, stream>>>(img, tgt, un, pt1, pt2, acc);
    ssim_kernel<<<dim3(16, NSLICE, 3), 256, 0, stream>>>(img, tgt, pt1, pt2, gb, acc);
    finalize_kernel<<<1, 1, 0, stream>>>(acc, out);
}

// Round 8
// 248.894 us; speedup vs baseline: 1.9478x; 1.1089x over previous
//
#include <hip/hip_runtime.h>
#include <cmath>
#include <cstring>

#define NUM_S   64
#define IMG_H   256
#define IMG_W   256
#define HWSZ    (IMG_H*IMG_W)          // 65536
#define BATCH   2
#define NPIX    (BATCH*HWSZ)           // 131072
#define NEL     (BATCH*NUM_S*HWSZ)     // 8388608
#define NSLICE  (BATCH*NUM_S)          // 128
#define VALID   246
#define EPS_F   1e-20f
#define C1_F    1e-4f
#define C2_F    9e-4f
#define RS      272                    // V_lds row stride in fp16 (544 B, 16B-aligned)

typedef __fp16 half8  __attribute__((ext_vector_type(8)));
typedef __fp16 fp16x2 __attribute__((ext_vector_type(2)));
using fragC = __attribute__((ext_vector_type(4))) float;  // 4 fp32

union H8 { half8 v; short s[8]; int i[4]; };
union PK { fp16x2 v; int i; };
union HS { __fp16 f; short s; };

struct GH { short h[11]; };            // fp16 bits of gaussian taps (sum ~= 1)

__device__ inline fp16x2 pkrtz(float a, float b) {
    return __builtin_amdgcn_cvt_pkrtz(a, b);   // 1 instr packs 2 values
}
__device__ inline float frcp(float x)  { return __builtin_amdgcn_rcpf(x); }
__device__ inline float flog2(float x) { return __builtin_amdgcn_logf(x); }   // v_log_f32 = log2
__device__ inline float fexp2(float x) { return __builtin_amdgcn_exp2f(x); }  // v_exp_f32 = 2^x

__device__ inline void block_atomic_add(float v, double* dst) {
    __shared__ float sm[8];
    __syncthreads();
    #pragma unroll
    for (int off = 32; off; off >>= 1) v += __shfl_down(v, off, 64);
    int lane = threadIdx.x & 63, w = threadIdx.x >> 6;
    if (lane == 0) sm[w] = v;
    __syncthreads();
    if (threadIdx.x == 0) {
        double s = 0.0;
        int nw = blockDim.x >> 6;
        for (int i = 0; i < nw; ++i) s += (double)sm[i];
        atomicAdd(dst, s);
    }
}

// Kernel 1: per-pixel softmax-prefix scan over slices, NO online max:
// e = exp(2(x+g)) <= 2e15 and den <= 1.3e17 fit fp32, so the rescale is
// unnecessary. Gumbel folded: exp(2g) = w^-2, w = eps - ln(u+eps).
// Divisions -> v_rcp. float2 = 2 pixels/thread, prefetch depth 2.
__global__ __launch_bounds__(256) void scan_kernel(
    const float* __restrict__ img, const float* __restrict__ tgt,
    const float* __restrict__ un,
    float2* __restrict__ pt1, float2* __restrict__ pt2,
    double* __restrict__ acc)
{
    const int HW2 = HWSZ / 2;
    int tid = blockIdx.x * 256 + threadIdx.x;
    bool bwd = tid >= (NPIX / 2);
    int p2 = bwd ? tid - NPIX / 2 : tid;
    int b   = p2 >> 15;
    int hw2 = p2 & (HW2 - 1);
    int idx  = b * (NUM_S * HW2) + hw2 + (bwd ? (NUM_S - 1) * HW2 : 0);
    int step = bwd ? -HW2 : HW2;
    const float2* __restrict__ img2 = (const float2*)img;
    const float2* __restrict__ tgt2 = (const float2*)tgt;
    const float2* __restrict__ un2  = (const float2*)un;
    float4* __restrict__ out4 = (float4*)(bwd ? pt2 : pt1);

    float num[2] = {0.f, 0.f}, den[2] = {0.f, 0.f}, tm[2] = {-INFINITY, -INFINITY};
    float l1x = 0.f, l1p = 0.f;

    float2 xb[2], ub[2], tb[2];
    xb[0] = img2[idx];        ub[0] = un2[idx];        tb[0] = tgt2[idx];
    xb[1] = img2[idx + step]; ub[1] = un2[idx + step]; tb[1] = tgt2[idx + step];

    for (int i = 0; i < NUM_S; ++i) {
        int buf = i & 1;
        float2 x = xb[buf], u = ub[buf], t = tb[buf];
        if (i + 2 < NUM_S) {
            int id2 = idx + 2 * step;
            xb[buf] = img2[id2]; ub[buf] = un2[id2]; tb[buf] = tgt2[id2];
        }
        float xc[2] = {x.x, x.y}, uc[2] = {u.x, u.y}, tc[2] = {t.x, t.y};
        float p[2];
        #pragma unroll
        for (int c = 0; c < 2; ++c) {
            // w = eps - ln(u+eps) > 0;  e = exp(2x) * w^-2
            float w = fmaf(flog2(uc[c] + EPS_F), -0.6931471805599453f, EPS_F);
            float r = frcp(w);
            float e = fexp2(xc[c] * 2.8853900817779268f) * (r * r);
            num[c] = fmaf(e, xc[c], num[c]);
            den[c] += e;
            p[c] = num[c] * frcp(den[c]);
            tm[c] = fmaxf(tm[c], tc[c]);
            if (!bwd) l1x += fabsf(xc[c] - tc[c]);
            l1p += fabsf(p[c] - tm[c]);
        }
        out4[idx] = make_float4(p[0], tm[0], p[1], tm[1]);
        idx += step;
    }
    block_atomic_add(l1x, &acc[0]);
    block_atomic_add(l1p, bwd ? &acc[2] : &acc[1]);
}

// Kernel 2: MFMA separable-Gaussian SSIM, fp16 fragments (same MFMA rate as
// bf16, 8x better precision, and v_cvt_pkrtz packs 2 values/instr).
// Stage 1: D16x16 = band(16x32) . B(field tile); V -> LDS fp16 (RS=272,
// pad cols [256,272) zeroed -- MFMA 0*garbage must stay finite).
// Stage 2: D = A(V rows, ds_read_b128) . band.  Epilogue: SSIM + mask + reduce.
__global__ __launch_bounds__(256) void ssim_kernel(
    const float* __restrict__ img, const float* __restrict__ tgt,
    const float2* __restrict__ pt1, const float2* __restrict__ pt2,
    GH gh, double* __restrict__ acc)
{
    __shared__ short Vl[5][16 * RS];       // 43520 B
    int pair  = blockIdx.z;
    int base  = blockIdx.y * HWSZ;
    int r0    = blockIdx.x * 16;
    int lane  = threadIdx.x & 63;
    int wid   = threadIdx.x >> 6;          // 0..3
    int q     = lane >> 4;                 // 0..3
    int n     = lane & 15;

    // band fragment: value g[(q*8+j) - n] (zero outside). A in stage 1
    // (A[m][k]=g[k-m]), B in stage 2 (B[k][n]=g[k-n]).
    H8 band;
    #pragma unroll
    for (int j = 0; j < 8; ++j) {
        int kk = q * 8 + j - n;
        short hv = 0;
        #pragma unroll
        for (int w = 0; w < 11; ++w) hv = (kk == w) ? gh.h[w] : hv;
        band.s[j] = hv;
    }

    // zero pad cols [256, RS): 8 dwords x 16 rows x 5 fields = 640 dwords
    for (int d = threadIdx.x; d < 640; d += 256) {
        int f = d >> 7, rm = d & 127, r = rm >> 3, cc = rm & 7;
        ((int*)Vl)[f * 2176 + r * 136 + 128 + cc] = 0;
    }

    bool clampR = (r0 == 240);
    const fragC zero = {0.f, 0.f, 0.f, 0.f};

    // ---- stage 1: 4 c-tiles per wave ----
    for (int it = 0; it < 4; ++it) {
        int c0 = (wid * 4 + it) * 16;
        int col = c0 + n;
        float xr[8], yr[8];
        if (pair == 0) {
            if (!clampR) {
                const float* px = img + base + (r0 + q * 8) * IMG_W + col;
                const float* py = tgt + base + (r0 + q * 8) * IMG_W + col;
                #pragma unroll
                for (int j = 0; j < 8; ++j) { xr[j] = px[j * IMG_W]; yr[j] = py[j * IMG_W]; }
            } else {
                #pragma unroll
                for (int j = 0; j < 8; ++j) {
                    int rr = min(r0 + q * 8 + j, IMG_H - 1);
                    xr[j] = img[base + rr * IMG_W + col];
                    yr[j] = tgt[base + rr * IMG_W + col];
                }
            }
        } else {
            const float2* __restrict__ pp = (pair == 1 ? pt1 : pt2) + base;
            if (!clampR) {
                const float2* p0 = pp + (r0 + q * 8) * IMG_W + col;
                #pragma unroll
                for (int j = 0; j < 8; ++j) { float2 w = p0[j * IMG_W]; xr[j] = w.x; yr[j] = w.y; }
            } else {
                #pragma unroll
                for (int j = 0; j < 8; ++j) {
                    int rr = min(r0 + q * 8 + j, IMG_H - 1);
                    float2 w = pp[rr * IMG_W + col];
                    xr[j] = w.x; yr[j] = w.y;
                }
            }
        }
        H8 fX, fY, fXX, fYY, fXY;
        #pragma unroll
        for (int j = 0; j < 8; j += 2) {
            PK a;
            a.v = pkrtz(xr[j], xr[j+1]);                     fX.i[j>>1]  = a.i;
            a.v = pkrtz(yr[j], yr[j+1]);                     fY.i[j>>1]  = a.i;
            a.v = pkrtz(xr[j]*xr[j], xr[j+1]*xr[j+1]);       fXX.i[j>>1] = a.i;
            a.v = pkrtz(yr[j]*yr[j], yr[j+1]*yr[j+1]);       fYY.i[j>>1] = a.i;
            a.v = pkrtz(xr[j]*yr[j], xr[j+1]*yr[j+1]);       fXY.i[j>>1] = a.i;
        }
        fragC v0 = __builtin_amdgcn_mfma_f32_16x16x32_f16(band.v, fX.v,  zero, 0, 0, 0);
        fragC v1 = __builtin_amdgcn_mfma_f32_16x16x32_f16(band.v, fY.v,  zero, 0, 0, 0);
        fragC v2 = __builtin_amdgcn_mfma_f32_16x16x32_f16(band.v, fXX.v, zero, 0, 0, 0);
        fragC v3 = __builtin_amdgcn_mfma_f32_16x16x32_f16(band.v, fYY.v, zero, 0, 0, 0);
        fragC v4 = __builtin_amdgcn_mfma_f32_16x16x32_f16(band.v, fXY.v, zero, 0, 0, 0);
        #pragma unroll
        for (int reg = 0; reg < 4; ++reg) {
            int ro = (q * 4 + reg) * RS + col;   // C-layout: row=q*4+reg, col=n
            HS cv;
            cv.f = (__fp16)v0[reg]; Vl[0][ro] = cv.s;
            cv.f = (__fp16)v1[reg]; Vl[1][ro] = cv.s;
            cv.f = (__fp16)v2[reg]; Vl[2][ro] = cv.s;
            cv.f = (__fp16)v3[reg]; Vl[3][ro] = cv.s;
            cv.f = (__fp16)v4[reg]; Vl[4][ro] = cv.s;
        }
    }
    __syncthreads();

    // ---- stage 2 + epilogue: 4 c-tiles per wave ----
    float lsum = 0.f;
    for (int it = 0; it < 4; ++it) {
        int c0 = (wid * 4 + it) * 16;
        int ao = n * RS + c0 + q * 8;      // A[m=n][k=q*8+j], 16B-aligned
        H8 a0, a1, a2, a3, a4;
        *(int4*)a0.i = *(const int4*)&Vl[0][ao];
        *(int4*)a1.i = *(const int4*)&Vl[1][ao];
        *(int4*)a2.i = *(const int4*)&Vl[2][ao];
        *(int4*)a3.i = *(const int4*)&Vl[3][ao];
        *(int4*)a4.i = *(const int4*)&Vl[4][ao];
        fragC o0 = __builtin_amdgcn_mfma_f32_16x16x32_f16(a0.v, band.v, zero, 0, 0, 0);
        fragC o1 = __builtin_amdgcn_mfma_f32_16x16x32_f16(a1.v, band.v, zero, 0, 0, 0);
        fragC o2 = __builtin_amdgcn_mfma_f32_16x16x32_f16(a2.v, band.v, zero, 0, 0, 0);
        fragC o3 = __builtin_amdgcn_mfma_f32_16x16x32_f16(a3.v, band.v, zero, 0, 0, 0);
        fragC o4 = __builtin_amdgcn_mfma_f32_16x16x32_f16(a4.v, band.v, zero, 0, 0, 0);
        #pragma unroll
        for (int reg = 0; reg < 4; ++reg) {
            int r = r0 + q * 4 + reg;
            int c = c0 + n;
            if (r < VALID && c < VALID) {
                float m1 = o0[reg], m2 = o1[reg];
                float s11 = o2[reg] - m1 * m1;
                float s22 = o3[reg] - m2 * m2;
                float s12 = o4[reg] - m1 * m2;
                float nv = (2.f * m1 * m2 + C1_F) * (2.f * s12 + C2_F);
                float dv = (m1 * m1 + m2 * m2 + C1_F) * (s11 + s22 + C2_F);
                lsum += nv * frcp(dv);
            }
        }
    }
    block_atomic_add(lsum, &acc[3 + pair]);
}

__global__ void finalize_kernel(const double* __restrict__ acc,
                                float* __restrict__ out) {
    double l1 = (acc[0] + acc[1] + acc[2]) / (double)NEL;
    double ss = (acc[3] + acc[4] + acc[5]) /
                ((double)NSLICE * (double)VALID * (double)VALID);
    out[0] = (float)(3.0 + l1 - ss);
}

// host float -> fp16 bits, RNE (taps are normal-range)
static unsigned short f32_to_f16(float f) {
    unsigned u; memcpy(&u, &f, 4);
    unsigned s = (u >> 16) & 0x8000u;
    int e = (int)((u >> 23) & 0xff) - 127 + 15;
    unsigned m = u & 0x7fffffu;
    unsigned h = s | ((unsigned)e << 10) | (m >> 13);
    unsigned rem = m & 0x1fffu;
    if (rem > 0x1000u || (rem == 0x1000u && (h & 1))) h++;
    return (unsigned short)h;
}
static double f16_to_d(unsigned short h) {
    unsigned e = (h >> 10) & 0x1f, m = h & 0x3ffu;
    return ldexp((double)(m + 1024), (int)e - 25);
}

extern "C" void kernel_launch(void* const* d_in, const int* in_sizes, int n_in,
                              void* d_out, int out_size, void* d_ws, size_t ws_size,
                              hipStream_t stream) {
    const float* img = (const float*)d_in[0];
    const float* tgt = (const float*)d_in[1];
    const float* un  = (const float*)d_in[2];
    float* out = (float*)d_out;

    float2* pt1 = (float2*)d_ws;           // 64 MB
    float2* pt2 = pt1 + NEL;               // 64 MB
    double* acc = (double*)(pt2 + NEL);

    (void)hipMemsetAsync(acc, 0, 6 * sizeof(double), stream);

    // gaussian(11, 1.5) in double; renormalize so fp16 taps sum to ~1
    GH gh;
    {
        double g[11], s = 0.0;
        for (int i = 0; i < 11; ++i) { double d = i - 5; g[i] = exp(-d * d / 4.5); s += g[i]; }
        for (int i = 0; i < 11; ++i) g[i] /= s;
        for (int iter = 0; iter < 3; ++iter) {
            double sb = 0.0;
            unsigned short h[11];
            for (int i = 0; i < 11; ++i) { h[i] = f32_to_f16((float)g[i]); sb += f16_to_d(h[i]); }
            for (int i = 0; i < 11; ++i) { g[i] /= sb; gh.h[i] = (short)h[i]; }
        }
    }

    scan_kernel<<<NPIX / 256, 256, 0, stream>>>(img, tgt, un, pt1, pt2, acc);
    ssim_kernel<<<dim3(16, NSLICE, 3), 256, 0, stream>>>(img, tgt, pt1, pt2, gh, acc);
    finalize_kernel<<<1, 1, 0, stream>>>(acc, out);
}